// Round 3
// baseline (27.379 us; speedup 1.0000x reference)
//
#include <hip/hip_runtime.h>
#include <math.h>

// B=256, K=51, N=8192. out = MULT * sum_{b,d} sqrt(q[b,d]),
// q[b,d] = w_b^T G_d w_b = sum_n (sum_k w[b,k]*bs[k,n,d])^2,  w = y_hat - y.
// (face cancels; EPS cross-term ~1e-6 relative -> dropped, validated earlier.)
//
// Round-3 structural move: never materialize G or chunk-partials. Compute the
// projection u[b,n,d] directly with MFMA and square-accumulate in-register.
// Kills the 3 MB partial write + 3 MB strided re-read + the whole latency-
// bound reduce phase of the old K2.
//
// Two dispatches:
//   K1 pl_init (9 blocks): blocks 0..7 precompute w as a bf16 hi/lo split
//      (w = hi + lo, residual ~2^-17 rel, 256x below the bf16-bs noise that
//      already passes) into w_hi/w_lo [256][64] (k>=51 zero). Block 8 zeroes
//      pq[768] + ctr. Kernel-boundary visibility makes this race-free.
//   K2 pl_direct (192 blocks = 3 d x 64 chunks of 128 points):
//      stage bs chunk transposed [n][k] in LDS (XOR-swizzled subblocks),
//      A-frags (w hi/lo) straight from global (64 KB, LLC-resident),
//      u = (w_hi + w_lo) . bs accumulated in one f32 MFMA acc, then
//      qacc += u^2; 16-lane shuffle reduce; atomicAdd pq[d*256+b]
//      (device-scope = LLC, fence-free). Completion: round-2-proven
//      release-ticket; last block (old==191) acquires once and sqrt-sums
//      pq via agent-scope loads. No spins, no L2 invalidates.
#define NPTS     8192
#define KDIM     51
#define KPAD     64
#define CHUNKS   64
#define CHUNK_N  128
#define MULT     0.0025f
#define NBLK     (3 * CHUNKS)   // 192
#define LK       72             // bs_lds row stride in bf16 (16B-aligned rows)

typedef short short8  __attribute__((ext_vector_type(8)));
typedef float float4v __attribute__((ext_vector_type(4)));

// RNE f32 -> bf16 bits (inputs are normal floats; NaN path irrelevant)
__device__ __forceinline__ unsigned short f32_to_bf16(float f) {
    unsigned int u = __float_as_uint(f);
    unsigned int r = u + 0x7FFFu + ((u >> 16) & 1u);
    return (unsigned short)(r >> 16);
}

// ---------------------------------------------------------------------------
// Kernel 1: init. Blocks 0..7: w hi/lo split (each 408 float4s of the flat
// 13056-element y arrays; 8*408*4 = 13056 exactly). Block 8: zero pq/ctr and
// the k=51..63 pad columns of w_hi/w_lo.
// ---------------------------------------------------------------------------
__global__ __launch_bounds__(256) void pl_init(
    const float* __restrict__ yh, const float* __restrict__ yv,
    unsigned short* __restrict__ w_hi, unsigned short* __restrict__ w_lo,
    float* __restrict__ pq, unsigned int* __restrict__ ctr) {
  const int bx = blockIdx.x, tid = threadIdx.x;
  if (bx == 8) {
    pq[tid] = 0.0f; pq[256 + tid] = 0.0f; pq[512 + tid] = 0.0f;
    if (tid == 0) ctr[0] = 0u;
    for (int i = tid; i < 256 * (KPAD - KDIM); i += 256) {
      int b = i / (KPAD - KDIM), k = KDIM + i % (KPAD - KDIM);
      w_hi[b * KPAD + k] = 0; w_lo[b * KPAD + k] = 0;
    }
    return;
  }
  for (int i = tid; i < 408; i += 256) {
    int idx4 = bx * 408 + i;
    float4v h = *(const float4v*)&yh[idx4 * 4];
    float4v v = *(const float4v*)&yv[idx4 * 4];
#pragma unroll
    for (int j = 0; j < 4; ++j) {
      int e = idx4 * 4 + j;
      int b = e / KDIM, k = e - b * KDIM;
      float w = h[j] - v[j];
      unsigned short hi = f32_to_bf16(w);
      float lo = w - __uint_as_float((unsigned int)hi << 16);
      w_hi[b * KPAD + k] = hi;
      w_lo[b * KPAD + k] = f32_to_bf16(lo);
    }
  }
}

// ---------------------------------------------------------------------------
// Kernel 2: direct projection. Block (d, chunk): u[b, n] for all 256 b over
// 128 points of one component d.
// MFMA m89-verified roles: D[row][col] = A[m][k]*B[k][n]; A-frag m=lane&15,
// k=(lane>>4)*8+j; B-frag n=lane&15, k contiguous; C row=(lane>>4)*4+reg
// (A side), col=lane&15 (B side). First arg = w (row=b), second = bs (col=n).
// bs_lds[n][kk]: kk = k ^ (8*((n>>1)&7)) — XOR on 8-elem subblocks keeps
// ds_read_b128 16B-aligned and spreads the staged u32 pair-writes to ~4-way.
// ---------------------------------------------------------------------------
__global__ __launch_bounds__(256) void pl_direct(
    const float* __restrict__ bs,
    const unsigned short* __restrict__ w_hi,
    const unsigned short* __restrict__ w_lo,
    float* __restrict__ pq, unsigned int* __restrict__ ctr,
    float* __restrict__ out) {
  __shared__ unsigned short bs_lds[CHUNK_N * LK];
  __shared__ unsigned int lflag;
  __shared__ float redw[4];

  const int bx  = blockIdx.x;
  const int d   = bx / CHUNKS;
  const int n0  = (bx % CHUNKS) * CHUNK_N;
  const int tid = threadIdx.x;
  const int wave = tid >> 6, lane = tid & 63;
  const int m16 = lane & 15, quad = lane >> 4;

  // A-fragments (w hi/lo) straight from global; 16B-aligned short8 loads.
  short8 ah[2][4], al[2][4];   // [kstep][mtile]
#pragma unroll
  for (int ks = 0; ks < 2; ++ks)
#pragma unroll
    for (int mt = 0; mt < 4; ++mt) {
      int off = (wave * 64 + mt * 16 + m16) * KPAD + ks * 32 + quad * 8;
      ah[ks][mt] = *(const short8*)&w_hi[off];
      al[ks][mt] = *(const short8*)&w_lo[off];
    }

  // Stage bs chunk transposed to [n][k]. Per wave-instr: 64 consecutive n,
  // fixed k-pair -> two coalesced-class scalar loads 24576 floats apart;
  // one packed u32 LDS write (banks ~4-way after swizzle). d-sibling blocks
  // (bx +- 64, same XCD under %8 mapping) share the fetched lines.
  unsigned int* lds32 = (unsigned int*)bs_lds;
#pragma unroll
  for (int it = 0; it < 16; ++it) {
    int u  = it * 256 + tid;
    int n  = u & 127;
    int kp = u >> 7;            // k-pair index 0..31
    int k0 = kp * 2;
    float v0 = 0.0f, v1 = 0.0f;
    if (k0 < KDIM) {
      const float* p = bs + (size_t)k0 * (NPTS * 3) + (size_t)(n0 + n) * 3 + d;
      v0 = p[0];
      if (k0 + 1 < KDIM) v1 = p[NPTS * 3];
    }
    lds32[n * (LK / 2) + (kp ^ (((n >> 1) & 7) << 2))] =
        (unsigned int)f32_to_bf16(v0) | ((unsigned int)f32_to_bf16(v1) << 16);
  }
  __syncthreads();

  // MFMA: 8 n-tiles x 2 k-steps x 4 m-tiles x {hi,lo} = 128 MFMA / wave.
  float qacc[4][4] = {{0.f}};
#pragma unroll
  for (int nt = 0; nt < 8; ++nt) {
    float4v acc[4] = {{0.f,0.f,0.f,0.f}, {0.f,0.f,0.f,0.f},
                      {0.f,0.f,0.f,0.f}, {0.f,0.f,0.f,0.f}};
#pragma unroll
    for (int ks = 0; ks < 2; ++ks) {
      const int nr = nt * 16 + m16;
      const int kk = (ks * 32 + quad * 8) ^ (((nr >> 1) & 7) << 3);
      short8 bf = *(const short8*)&bs_lds[nr * LK + kk];
#pragma unroll
      for (int mt = 0; mt < 4; ++mt)
        acc[mt] = __builtin_amdgcn_mfma_f32_16x16x32_bf16(ah[ks][mt], bf, acc[mt], 0, 0, 0);
#pragma unroll
      for (int mt = 0; mt < 4; ++mt)
        acc[mt] = __builtin_amdgcn_mfma_f32_16x16x32_bf16(al[ks][mt], bf, acc[mt], 0, 0, 0);
    }
#pragma unroll
    for (int mt = 0; mt < 4; ++mt)
#pragma unroll
      for (int r = 0; r < 4; ++r)
        qacc[mt][r] = fmaf(acc[mt][r], acc[mt][r], qacc[mt][r]);
  }

  // Reduce over the 16 lanes of each quad-group (they hold the 16 n-cols of
  // each tile); lane m16==0 then owns q-partials for b = wave*64+mt*16+quad*4+r.
#pragma unroll
  for (int mt = 0; mt < 4; ++mt)
#pragma unroll
    for (int r = 0; r < 4; ++r) {
      float v = qacc[mt][r];
      v += __shfl_xor(v, 1, 16);
      v += __shfl_xor(v, 2, 16);
      v += __shfl_xor(v, 4, 16);
      v += __shfl_xor(v, 8, 16);
      qacc[mt][r] = v;
    }
  if (m16 == 0) {
#pragma unroll
    for (int mt = 0; mt < 4; ++mt)
#pragma unroll
      for (int r = 0; r < 4; ++r)
        atomicAdd(&pq[d * 256 + wave * 64 + mt * 16 + quad * 4 + r], qacc[mt][r]);
  }
  __syncthreads();   // drains each wave's outstanding atomics before release

  if (tid == 0) {
    unsigned int old = __hip_atomic_fetch_add(ctr, 1u, __ATOMIC_RELEASE,
                                              __HIP_MEMORY_SCOPE_AGENT);
    lflag = (old == (NBLK - 1)) ? 1u : 0u;
  }
  __syncthreads();
  if (lflag == 0u) return;   // 191 blocks exit immediately; no spin anywhere

  // Last block: single acquire, then sqrt-sum of all 768 q values.
  if (tid == 0)
    (void)__hip_atomic_load(ctr, __ATOMIC_ACQUIRE, __HIP_MEMORY_SCOPE_AGENT);
  __syncthreads();

  float s = 0.0f;
#pragma unroll
  for (int i = 0; i < 3; ++i) {
    // Agent-scope loads bypass L1/L2 (this XCD's L2 may hold stale zeros
    // from the init block); values are final once ctr hit 192.
    float q = __hip_atomic_load(&pq[i * 256 + tid], __ATOMIC_RELAXED,
                                __HIP_MEMORY_SCOPE_AGENT);
    s += sqrtf(q);
  }
  for (int off = 32; off; off >>= 1) s += __shfl_down(s, off, 64);
  if ((tid & 63) == 0) redw[tid >> 6] = s;
  __syncthreads();
  if (tid == 0)
    out[0] = (redw[0] + redw[1] + redw[2] + redw[3]) * MULT;
}

extern "C" void kernel_launch(void* const* d_in, const int* in_sizes, int n_in,
                              void* d_out, int out_size, void* d_ws, size_t ws_size,
                              hipStream_t stream) {
  const float* y_hat = (const float*)d_in[0];   // [256,51]
  const float* y     = (const float*)d_in[1];   // [256,51]
  // d_in[2] = face [8192,3] — cancels algebraically, unused
  const float* bs    = (const float*)d_in[3];   // [51,8192,3]
  float* out = (float*)d_out;

  unsigned short* w_hi = (unsigned short*)d_ws;            // 256*64 bf16 = 32 KB
  unsigned short* w_lo = w_hi + 256 * KPAD;                // 32 KB
  float* pq            = (float*)(w_lo + 256 * KPAD);      // 768 floats
  unsigned int* ctr    = (unsigned int*)(pq + 768);        // 1 uint

  pl_init<<<9, 256, 0, stream>>>(y_hat, y, w_hi, w_lo, pq, ctr);
  pl_direct<<<NBLK, 256, 0, stream>>>(bs, w_hi, w_lo, pq, ctr, y_hat /*unused*/ == nullptr ? out : out);
}